// Round 6
// baseline (82.167 us; speedup 1.0000x reference)
//
#include <hip/hip_runtime.h>

#define DD 192
#define HH 224
#define WW 192
#define HWN (HH*WW)              // 43008
#define PLANE ((size_t)DD*HWN)   // 8257536
#define DSEG 16                  // d outputs per kA block
#define NSTEP (DSEG + 8)         // 24 d-steps per block
#define HS 28                    // h outputs per kB block
#define NHS 8                    // 8 * 28 = 224
#define NPART (DD*NHS)           // 1536

// ---------------- kA: products + W-tap + D-tap, barrier-free + pipelined --
// Wave owns (h, 64-col group), marches d. Wave-private LDS slab (72 cols,
// double-buffered). Step s: issue loads for s+1 -> compute step s from
// buf -> ds_write prefetched slab to buf^1. No barriers, no inline asm.
__global__ __launch_bounds__(192) void kA(
    const float* __restrict__ I, const float* __restrict__ J,
    float4* __restrict__ F4, float* __restrict__ F1,
    int chunk_base, int chunk)
{
    const int h  = blockIdx.x;                 // 0..223
    const int d0 = chunk_base + blockIdx.y * DSEG;
    const int wv = threadIdx.x >> 6;           // 0..2
    const int l  = threadIdx.x & 63;
    const int w0 = wv << 6;

    __shared__ float stg[3][2][2][72];         // [wave][buf][field][slot]
    float (*st)[2][72] = stg[wv];              // wave-private view

    // zero both buffers once (pads stay zero; masked lanes never write them)
#pragma unroll
    for (int b = 0; b < 2; ++b) {
        st[b][0][l] = 0.f; st[b][1][l] = 0.f;
        if (l < 8) { st[b][0][64 + l] = 0.f; st[b][1][64 + l] = 0.f; }
    }

    const size_t rowb = (size_t)h * WW;
    const int  cm = w0 - 4 + l;                // main staged col -> slot l
    const int  ch = w0 + 60 + l;               // halo staged col -> slot 64+l
    const bool vm = (cm >= 0) && (cm < WW);
    const bool vh = (l < 8) && (ch < WW);

    float r0[9], r1[9], r2[9], r3[9], r4[9];
    float S0=0.f,S1=0.f,S2=0.f,S3=0.f,S4=0.f;
#pragma unroll
    for (int k = 0; k < 9; ++k) { r0[k]=0.f; r1[k]=0.f; r2[k]=0.f; r3[k]=0.f; r4[k]=0.f; }

    // prologue: load slab for s=0 (din = d0-4), write to buf 0
    {
        int din = d0 - 4;
        bool pv = (din >= 0) && (din < DD);
        float pI=0.f, pJ=0.f, qI=0.f, qJ=0.f;
        const float* Ip = I + (size_t)din * HWN + rowb;
        const float* Jp = J + (size_t)din * HWN + rowb;
        if (pv && vm) { pI = Ip[cm]; pJ = Jp[cm]; }
        if (pv && vh) { qI = Ip[ch]; qJ = Jp[ch]; }
        if (vm) { st[0][0][l] = pI;      st[0][1][l] = pJ; }
        if (vh) { st[0][0][64 + l] = qI; st[0][1][64 + l] = qJ; }
    }

    for (int bse = 0; bse < 36; bse += 18) {
#pragma unroll
        for (int k = 0; k < 18; ++k) {
            int s = bse + k;
            if (s < NSTEP) {                   // uniform
                const int slot = k % 9;        // compile-time (18%9==0)
                const int buf  = k & 1;        // compile-time (18 even)

                // 1) prefetch slab for step s+1 (loads in flight over compute)
                float nI=0.f, nJ=0.f, mI=0.f, mJ=0.f;
                {
                    int din = d0 - 3 + s;      // (d0-4) + (s+1)
                    bool pv = (s + 1 < NSTEP) && (din >= 0) && (din < DD);
                    const float* Ip = I + (size_t)din * HWN + rowb;
                    const float* Jp = J + (size_t)din * HWN + rowb;
                    if (pv && vm) { nI = Ip[cm]; nJ = Jp[cm]; }
                    if (pv && vh) { mI = Ip[ch]; mJ = Jp[ch]; }
                }

                // 2) W-tap from staged slab: window sums of the 5 products
                float a0=0.f,a1=0.f,a2=0.f,a3=0.f,a4=0.f;
#pragma unroll
                for (int j = 0; j < 9; ++j) {
                    float vi = st[buf][0][l + j];
                    float vj = st[buf][1][l + j];
                    a0 += vi;
                    a1 += vj;
                    a2 = fmaf(vi, vi, a2);
                    a3 = fmaf(vj, vj, a3);
                    a4 = fmaf(vi, vj, a4);
                }

                // D-ring (static slot)
                S0 += a0 - r0[slot]; r0[slot] = a0;
                S1 += a1 - r1[slot]; r1[slot] = a1;
                S2 += a2 - r2[slot]; r2[slot] = a2;
                S3 += a3 - r3[slot]; r3[slot] = a3;
                S4 += a4 - r4[slot]; r4[slot] = a4;

                int dc = d0 - 8 + s;           // din - 4
                if (s >= 8) {                  // uniform; dc < d0+DSEG always
                    size_t o = (size_t)(dc - chunk_base) * HWN + rowb
                             + (size_t)(w0 + l);
                    F4[o] = make_float4(S0, S1, S2, S3);
                    F1[o] = S4;
                }

                // 3) stage prefetched slab into the other buffer
                if (vm) { st[buf^1][0][l] = nI;      st[buf^1][1][l] = nJ; }
                if (vh) { st[buf^1][0][64 + l] = mI; st[buf^1][1][64 + l] = mJ; }
            }
        }
    }
}

// ---------------- kB: H-tap (reg ring) + NCC math; no LDS in march --------
// thread owns (d,w), marches h. Packed loads: float4 (S0-S3) + float (S4).
__global__ __launch_bounds__(192) void kB(
    const float4* __restrict__ F4, const float* __restrict__ F1,
    double* __restrict__ partials, int chunk_base, int chunk)
{
    const int drel = blockIdx.x;
    const int hs   = blockIdx.y;
    const int w    = threadIdx.x;
    const int h0   = hs * HS;
    const float4* __restrict__ B4 = F4 + (size_t)drel * HWN + (size_t)w;
    const float*  __restrict__ B1 = F1 + (size_t)drel * HWN + (size_t)w;

    float r0[9], r1[9], r2[9], r3[9], r4[9];
    float S0=0.f,S1=0.f,S2=0.f,S3=0.f,S4=0.f;
#pragma unroll
    for (int k = 0; k < 9; ++k) { r0[k]=0.f; r1[k]=0.f; r2[k]=0.f; r3[k]=0.f; r4[k]=0.f; }

    float acc = 0.f;

    float c0=0.f,c1=0.f,c2=0.f,c3=0.f,c4=0.f;
    {
        int hin = h0 - 4;
        if (hin >= 0) {
            size_t o = (size_t)hin * WW;
            float4 v = B4[o];
            c0=v.x; c1=v.y; c2=v.z; c3=v.w; c4=B1[o];
        }
    }

    for (int bse = 0; bse < 36; bse += 9) {
#pragma unroll
        for (int k = 0; k < 9; ++k) {
            int s = bse + k;

            float n0=0.f,n1=0.f,n2=0.f,n3=0.f,n4=0.f;
            int hin1 = h0 - 3 + s;
            if (s < 35 && hin1 >= 0 && hin1 < HH) {
                size_t o = (size_t)hin1 * WW;
                float4 v = B4[o];
                n0=v.x; n1=v.y; n2=v.z; n3=v.w; n4=B1[o];
            }

            S0 += c0 - r0[k]; r0[k] = c0;
            S1 += c1 - r1[k]; r1[k] = c1;
            S2 += c2 - r2[k]; r2[k] = c2;
            S3 += c3 - r3[k]; r3[k] = c3;
            S4 += c4 - r4[k]; r4[k] = c4;

            if (s >= 8) {
                const float inv = 1.0f / 729.0f;
                float cross = S4 - S0 * S1 * inv;
                float varI  = S2 - S0 * S0 * inv;
                float varJ  = S3 - S1 * S1 * inv;
                acc += cross * cross / (varI * varJ + 1e-5f);
            }

            c0=n0; c1=n1; c2=n2; c3=n3; c4=n4;
        }
    }

    __shared__ float red[192];
    red[w] = acc;
    __syncthreads();
#pragma unroll
    for (int off = 96; off >= 3; off >>= 1) {
        if (w < off) red[w] += red[w + off];
        __syncthreads();
    }
    if (w == 0) {
        int d = chunk_base + drel;
        partials[d * NHS + hs] = (double)(red[0] + red[1] + red[2]);
    }
}

// ---------------- k3: final reduction of 1536 partials --------------------
__global__ __launch_bounds__(256) void k3_reduce(
    const double* __restrict__ partials, float* __restrict__ out)
{
    __shared__ double red[256];
    int t = threadIdx.x;
    double a = 0.0;
    for (int i = t; i < NPART; i += 256) a += partials[i];
    red[t] = a;
    __syncthreads();
    for (int off = 128; off > 0; off >>= 1) {
        if (t < off) red[t] += red[t + off];
        __syncthreads();
    }
    if (t == 0) out[0] = (float)(-red[0] / (double)PLANE);
}

extern "C" void kernel_launch(void* const* d_in, const int* in_sizes, int n_in,
                              void* d_out, int out_size, void* d_ws, size_t ws_size,
                              hipStream_t stream)
{
    const float* I = (const float*)d_in[0];
    const float* J = (const float*)d_in[1];
    float* out = (float*)d_out;

    double* partials = (double*)d_ws;
    const size_t part_bytes = 16384;               // 1536*8 rounded up; 16B align

    // Largest d-chunk (multiple of DSEG=16, divisor of 192) fitting in ws.
    static const int chunks[6] = {192, 96, 64, 48, 32, 16};
    int chunk = 16;
    for (int i = 0; i < 6; ++i) {
        size_t need = part_bytes + 20ull * (size_t)chunks[i] * HWN;  // 16+4 B/voxel
        if (need <= ws_size) { chunk = chunks[i]; break; }
    }

    float4* F4 = (float4*)((char*)d_ws + part_bytes);
    float*  F1 = (float*)((char*)d_ws + part_bytes + 16ull * (size_t)chunk * HWN);

    for (int cb = 0; cb < DD; cb += chunk) {
        kA<<<dim3(HH, chunk / DSEG), dim3(192), 0, stream>>>(I, J, F4, F1, cb, chunk);
        kB<<<dim3(chunk, NHS), dim3(192), 0, stream>>>(F4, F1, partials, cb, chunk);
    }
    k3_reduce<<<dim3(1), dim3(256), 0, stream>>>(partials, out);
}

// Round 9
// 78.902 us; speedup vs baseline: 1.0414x; 1.0414x over previous
//
#include <hip/hip_runtime.h>

#define DD 192
#define HH 224
#define WW 192
#define HWN (HH*WW)              // 43008
#define PLANE ((size_t)DD*HWN)   // 8257536
#define DSEG 32                  // d outputs per kA block
#define HS 28                    // h outputs per kB block
#define NHS 8                    // 8 * 28 = 224
#define NPART (DD*NHS)           // 1536

// ---------------- kA: products + W-tap + D-tap, BARRIER-FREE --------------
// Each 64-lane wave owns (h, 64-col w-group) and marches d. It stages a
// 72-col slab of I and J in WAVE-PRIVATE LDS (intra-wave ordering via
// lgkmcnt only — no __syncthreads in the march), does the 9-tap W-window
// from LDS, forms the 5 products' window sums in-register, then a 9-deep
// D-ring (static slots) and writes the 5 DW-summed fields coalesced.
__global__ __launch_bounds__(192) void kA(
    const float* __restrict__ I, const float* __restrict__ J,
    float* __restrict__ F, int chunk_base, int chunk)
{
    const int h  = blockIdx.x;                 // 0..223
    const int d0 = chunk_base + blockIdx.y * DSEG;
    const int wv = threadIdx.x >> 6;           // 0..2
    const int l  = threadIdx.x & 63;
    const int w0 = wv << 6;

    __shared__ float stg[3][2][2][72];         // [wave][buf][field][slot]
    float (*st)[2][72] = stg[wv];              // wave-private view

    // pre-zero this wave's slots once; masked lanes never overwrite pads
#pragma unroll
    for (int b = 0; b < 2; ++b) {
        st[b][0][l] = 0.f; st[b][1][l] = 0.f;
        if (l < 8) { st[b][0][64 + l] = 0.f; st[b][1][64 + l] = 0.f; }
    }
    // no sync: nothing crosses waves

    const size_t fs   = (size_t)chunk * HWN;
    const size_t rowb = (size_t)h * WW;
    const int  cm = w0 - 4 + l;                // main staged col -> slot l
    const int  ch = w0 + 60 + l;               // halo staged col -> slot 64+l
    const bool vm = (cm >= 0) && (cm < WW);
    const bool vh = (l < 8) && (ch < WW);

    float r0[9], r1[9], r2[9], r3[9], r4[9];
    float S0=0.f,S1=0.f,S2=0.f,S3=0.f,S4=0.f;
#pragma unroll
    for (int k = 0; k < 9; ++k) { r0[k]=0.f; r1[k]=0.f; r2[k]=0.f; r3[k]=0.f; r4[k]=0.f; }

    for (int bse = 0; bse < 54; bse += 18) {   // runtime outer: no code bloat
#pragma unroll
        for (int k = 0; k < 18; ++k) {
            int s = bse + k;
            if (s < DSEG + 8) {                // uniform
                const int slot = (k < 9) ? k : k - 9;   // compile-time
                const int buf  = k & 1;                 // compile-time
                int din = d0 - 4 + s;
                float a0, a1, a2, a3, a4;
                if (din >= 0 && din < DD) {    // uniform per wave
                    const float* Ip = I + (size_t)din * HWN + rowb;
                    const float* Jp = J + (size_t)din * HWN + rowb;
                    if (vm) {
                        st[buf][0][l] = Ip[cm];
                        st[buf][1][l] = Jp[cm];
                    }
                    if (vh) {
                        st[buf][0][64 + l] = Ip[ch];
                        st[buf][1][64 + l] = Jp[ch];
                    }
                    a0=a1=a2=a3=a4=0.f;
#pragma unroll
                    for (int j = 0; j < 9; ++j) {
                        float vi = st[buf][0][l + j];
                        float vj = st[buf][1][l + j];
                        a0 += vi;
                        a1 += vj;
                        a2 = fmaf(vi, vi, a2);
                        a3 = fmaf(vj, vj, a3);
                        a4 = fmaf(vi, vj, a4);
                    }
                } else {
                    a0=a1=a2=a3=a4=0.f;        // zero-pad plane
                }
                S0 += a0 - r0[slot]; r0[slot] = a0;
                S1 += a1 - r1[slot]; r1[slot] = a1;
                S2 += a2 - r2[slot]; r2[slot] = a2;
                S3 += a3 - r3[slot]; r3[slot] = a3;
                S4 += a4 - r4[slot]; r4[slot] = a4;

                int dc = din - 4;
                if (dc >= d0 && dc < d0 + DSEG) {       // uniform
                    size_t o = (size_t)(dc - chunk_base) * HWN + rowb
                             + (size_t)(w0 + l);
                    F[o]        = S0;
                    F[fs + o]   = S1;
                    F[2*fs + o] = S2;
                    F[3*fs + o] = S3;
                    F[4*fs + o] = S4;
                }
            }
        }
    }
}

// ---------------- kB: H-tap (reg ring) + NCC math; no LDS in march --------
__global__ __launch_bounds__(192) void kB(
    const float* __restrict__ F, double* __restrict__ partials,
    int chunk_base, int chunk)
{
    const int drel = blockIdx.x;
    const int hs   = blockIdx.y;
    const int w    = threadIdx.x;
    const int h0   = hs * HS;
    const size_t fs = (size_t)chunk * HWN;
    const float* __restrict__ B = F + (size_t)drel * HWN + (size_t)w;

    float r0[9], r1[9], r2[9], r3[9], r4[9];
    float S0=0.f,S1=0.f,S2=0.f,S3=0.f,S4=0.f;
#pragma unroll
    for (int k = 0; k < 9; ++k) { r0[k]=0.f; r1[k]=0.f; r2[k]=0.f; r3[k]=0.f; r4[k]=0.f; }

    float acc = 0.f;

    float c0=0.f,c1=0.f,c2=0.f,c3=0.f,c4=0.f;
    {
        int hin = h0 - 4;
        if (hin >= 0) {
            size_t o = (size_t)hin * WW;
            c0=B[o]; c1=B[fs+o]; c2=B[2*fs+o]; c3=B[3*fs+o]; c4=B[4*fs+o];
        }
    }

    for (int bse = 0; bse < 36; bse += 9) {
#pragma unroll
        for (int k = 0; k < 9; ++k) {
            int s = bse + k;

            float n0=0.f,n1=0.f,n2=0.f,n3=0.f,n4=0.f;
            int hin1 = h0 - 3 + s;
            if (s < 35 && hin1 >= 0 && hin1 < HH) {
                size_t o = (size_t)hin1 * WW;
                n0=B[o]; n1=B[fs+o]; n2=B[2*fs+o]; n3=B[3*fs+o]; n4=B[4*fs+o];
            }

            S0 += c0 - r0[k]; r0[k] = c0;
            S1 += c1 - r1[k]; r1[k] = c1;
            S2 += c2 - r2[k]; r2[k] = c2;
            S3 += c3 - r3[k]; r3[k] = c3;
            S4 += c4 - r4[k]; r4[k] = c4;

            if (s >= 8) {
                const float inv = 1.0f / 729.0f;
                float cross = S4 - S0 * S1 * inv;
                float varI  = S2 - S0 * S0 * inv;
                float varJ  = S3 - S1 * S1 * inv;
                acc += cross * cross / (varI * varJ + 1e-5f);
            }

            c0=n0; c1=n1; c2=n2; c3=n3; c4=n4;
        }
    }

    __shared__ float red[192];
    red[w] = acc;
    __syncthreads();
#pragma unroll
    for (int off = 96; off >= 3; off >>= 1) {
        if (w < off) red[w] += red[w + off];
        __syncthreads();
    }
    if (w == 0) {
        int d = chunk_base + drel;
        partials[d * NHS + hs] = (double)(red[0] + red[1] + red[2]);
    }
}

// ---------------- k3: final reduction of 1536 partials --------------------
__global__ __launch_bounds__(256) void k3_reduce(
    const double* __restrict__ partials, float* __restrict__ out)
{
    __shared__ double red[256];
    int t = threadIdx.x;
    double a = 0.0;
    for (int i = t; i < NPART; i += 256) a += partials[i];
    red[t] = a;
    __syncthreads();
    for (int off = 128; off > 0; off >>= 1) {
        if (t < off) red[t] += red[t + off];
        __syncthreads();
    }
    if (t == 0) out[0] = (float)(-red[0] / (double)PLANE);
}

extern "C" void kernel_launch(void* const* d_in, const int* in_sizes, int n_in,
                              void* d_out, int out_size, void* d_ws, size_t ws_size,
                              hipStream_t stream)
{
    const float* I = (const float*)d_in[0];
    const float* J = (const float*)d_in[1];
    float* out = (float*)d_out;

    double* partials = (double*)d_ws;
    const size_t part_bytes = 16384;               // 1536*8 rounded up
    float* F = (float*)((char*)d_ws + part_bytes);

    // Largest d-chunk (multiple of DSEG, divisor of 192) fitting in ws.
    static const int chunks[4] = {192, 96, 64, 32};
    int chunk = 32;
    for (int i = 0; i < 4; ++i) {
        size_t need = part_bytes + 20ull * (size_t)chunks[i] * HWN;
        if (need <= ws_size) { chunk = chunks[i]; break; }
    }

    for (int cb = 0; cb < DD; cb += chunk) {
        kA<<<dim3(HH, chunk / DSEG), dim3(192), 0, stream>>>(I, J, F, cb, chunk);
        kB<<<dim3(chunk, NHS), dim3(192), 0, stream>>>(F, partials, cb, chunk);
    }
    k3_reduce<<<dim3(1), dim3(256), 0, stream>>>(partials, out);
}